// Round 5
// baseline (125.867 us; speedup 1.0000x reference)
//
#include <hip/hip_runtime.h>

typedef unsigned int u32;

#define HALF_T 2097152u   // 2048*2048/2
#define NPX 2048
#define NPOOL_BLOCKS 4096

// ---------------- threefry2x32 (JAX-exact, 20 rounds) ----------------
__host__ __device__ inline void tf2x32(u32 k0, u32 k1, u32& x0, u32& x1) {
  const u32 ks2 = k0 ^ k1 ^ 0x1BD11BDAu;
  x0 += k0; x1 += k1;
#define TFR(r) { x0 += x1; x1 = (x1 << (r)) | (x1 >> (32 - (r))); x1 ^= x0; }
  TFR(13) TFR(15) TFR(26) TFR(6)
  x0 += k1;  x1 += ks2 + 1u;
  TFR(17) TFR(29) TFR(16) TFR(24)
  x0 += ks2; x1 += k0 + 2u;
  TFR(13) TFR(15) TFR(26) TFR(6)
  x0 += k0;  x1 += k1 + 3u;
  TFR(17) TFR(29) TFR(16) TFR(24)
  x0 += k1;  x1 += ks2 + 4u;
  TFR(13) TFR(15) TFR(26) TFR(6)
  x0 += ks2; x1 += k0 + 5u;
#undef TFR
}

// Partitionable-threefry random bits for flat index t (size < 2^32 -> hi word 0):
// bits[t] = x0 ^ x1 of threefry2x32(key, (0, t)).
__device__ inline u32 pbits(u32 k0, u32 k1, u32 t) {
  u32 x0 = 0u, x1 = t;
  tf2x32(k0, k1, x0, x1);
  return x0 ^ x1;
}

__device__ inline float bits_to_uniform(u32 bits) {
  return __uint_as_float((bits >> 9) | 0x3F800000u) - 1.0f;
}

// -------- kernel 1: maxpool min/max partials only (no dn store) --------
// 4096 blocks x 256 threads; thread g covers pool rows (i, i+1024), 4 cols each.
__global__ __launch_bounds__(256) void k_pool_nostore(const float* __restrict__ coarse,
                                                      float* __restrict__ pmin,
                                                      float* __restrict__ pmax) {
  const u32 g = blockIdx.x * 256 + threadIdx.x;   // [0, 1048576)
  const int i  = g >> 10;                         // pool row in [0,1024)
  const int jj = g & 1023;                        // float4 col index
  const float4* r0 = (const float4*)(coarse + (size_t)(2*i       ) * 4096);
  const float4* r1 = (const float4*)(coarse + (size_t)(2*i + 1   ) * 4096);
  const float4* r2 = (const float4*)(coarse + (size_t)(2*i + 2048) * 4096);
  const float4* r3 = (const float4*)(coarse + (size_t)(2*i + 2049) * 4096);
  const float4 a = r0[jj], b = r1[jj], c = r2[jj], d = r3[jj];

  const float p0a = fmaxf(fmaxf(a.x, a.y), fmaxf(b.x, b.y));
  const float p0b = fmaxf(fmaxf(a.z, a.w), fmaxf(b.z, b.w));
  const float p1a = fmaxf(fmaxf(c.x, c.y), fmaxf(d.x, d.y));
  const float p1b = fmaxf(fmaxf(c.z, c.w), fmaxf(d.z, d.w));

  float lmin = fminf(fminf(p0a, p0b), fminf(p1a, p1b));
  float lmax = fmaxf(fmaxf(p0a, p0b), fmaxf(p1a, p1b));

  for (int off = 32; off > 0; off >>= 1) {
    lmin = fminf(lmin, __shfl_down(lmin, off, 64));
    lmax = fmaxf(lmax, __shfl_down(lmax, off, 64));
  }
  __shared__ float smin[4], smax[4];
  const int lane = threadIdx.x & 63, wv = threadIdx.x >> 6;
  if (lane == 0) { smin[wv] = lmin; smax[wv] = lmax; }
  __syncthreads();
  if (threadIdx.x == 0) {
    pmin[blockIdx.x] = fminf(fminf(smin[0], smin[1]), fminf(smin[2], smin[3]));
    pmax[blockIdx.x] = fmaxf(fmaxf(smax[0], smax[1]), fmaxf(smax[2], smax[3]));
  }
}

// -------- per-block redundant final reduce (partials sit in L2/L3) --------
__device__ inline float block_thr(const float* __restrict__ pmin,
                                  const float* __restrict__ pmax,
                                  int tid) {
  __shared__ float smin[16], smax[16], sthr;
  float lmin = INFINITY, lmax = -INFINITY;
#pragma unroll
  for (int k = 0; k < NPOOL_BLOCKS; k += 1024) {
    lmin = fminf(lmin, pmin[tid + k]);
    lmax = fmaxf(lmax, pmax[tid + k]);
  }
  for (int off = 32; off > 0; off >>= 1) {
    lmin = fminf(lmin, __shfl_down(lmin, off, 64));
    lmax = fmaxf(lmax, __shfl_down(lmax, off, 64));
  }
  const int lane = tid & 63, wv = tid >> 6;
  if (lane == 0) { smin[wv] = lmin; smax[wv] = lmax; }
  __syncthreads();
  if (tid == 0) {
    float gmin = smin[0], gmax = smax[0];
#pragma unroll
    for (int w = 1; w < 16; ++w) {
      gmin = fminf(gmin, smin[w]);
      gmax = fmaxf(gmax, smax[w]);
    }
    sthr = (gmax - gmin) / 2048.0f;
  }
  __syncthreads();
  return sthr;
}

// -------- adjacency evaluation from an LDS tile --------
// s[lc][lr] = dn[i = cbase-1+lc][j = rbase-1+lr]; thread center at lc=tx+1, lr=ty+1.
__device__ inline bool adj_eval(const float s[34][35], int tx, int ty,
                                int c, int rr, float thr) {
  const float ctr = s[tx+1][ty+1];
  const bool cge1 = (c  >= 1),    cle = (c  <= NPX - 2);
  const bool rge1 = (rr >= 1),    rle = (rr <= NPX - 2);
  bool a = false;
  if (cge1 && rge1)                    a |= (fabsf(s[tx  ][ty  ] - ctr) <= thr); // d[i-1,j-1]
  if (cge1 && cle && rge1 && rle)      a |= (fabsf(s[tx+2][ty  ] - ctr) <= thr); // d[i+1,j-1]
  if (cge1 && rle)                     a |= (fabsf(s[tx  ][ty+2] - ctr) <= thr); // d[i-1,j+1]
  if (cle  && rle)                     a |= (fabsf(s[tx+2][ty+2] - ctr) <= thr); // d[i+1,j+1]
  return a;
}

// dn recompute from coarse (L3-resident after k_pool_nostore's full pass).
__device__ inline float dn_compute(const float* __restrict__ coarse,
                                   int i, int j, u32 kn0, u32 kn1) {
  const float2* r0 = (const float2*)(coarse + (size_t)(2*i    ) * 4096);
  const float2* r1 = (const float2*)(coarse + (size_t)(2*i + 1) * 4096);
  float2 a = r0[j], b = r1[j];
  float p = fmaxf(fmaxf(a.x, a.y), fmaxf(b.x, b.y));
  return p + bits_to_uniform(pbits(kn0, kn1, (u32)(i * NPX + j)));
}

// -------- kernel 2: thr reduce + fused dn recompute + adjacency + dropout --------
// OUTPUT IS INT32 (reference returns bool).
__global__ __launch_bounds__(1024) void k_graph_fused(const float* __restrict__ coarse,
                                                      const float* __restrict__ pmin,
                                                      const float* __restrict__ pmax,
                                                      int* __restrict__ out,
                                                      u32 kn0, u32 kn1, u32 kd0, u32 kd1) {
  __shared__ float s0[34][35];
  __shared__ float s1[34][35];
  const int tid = threadIdx.y * 32 + threadIdx.x;
  const float thr = block_thr(pmin, pmax, tid);
  const int c0 = blockIdx.x * 32, r0 = blockIdx.y * 32;
  for (int idx = tid; idx < 34 * 34; idx += 1024) {
    const int lc = idx / 34, lr = idx - lc * 34;
    const int c = c0 - 1 + lc;        // dn row index (i)
    const int r = r0 - 1 + lr;        // dn col index (j), tile0
    float v0 = 0.f, v1 = 0.f;
    if ((unsigned)c < (unsigned)NPX) {
      if ((unsigned)r < (unsigned)NPX)      v0 = dn_compute(coarse, c, r, kn0, kn1);
      const int r2 = r + 1024;
      if ((unsigned)r2 < (unsigned)NPX)     v1 = dn_compute(coarse, c, r2, kn0, kn1);
    }
    s0[lc][lr] = v0;
    s1[lc][lr] = v1;
  }
  __syncthreads();
  const int tx = threadIdx.x, ty = threadIdx.y;
  const int c = c0 + tx, r = r0 + ty;          // out col / out row (first tile)
  const bool adj0 = adj_eval(s0, tx, ty, c, r,        thr);
  const bool adj1 = adj_eval(s1, tx, ty, c, r + 1024, thr);
  const u32 t0 = (u32)(r * NPX + c);
  // bernoulli(0.5): uniform < 0.5  <=>  top bit of bits == 0
  const bool keep0 = !(pbits(kd0, kd1, t0)          >> 31);
  const bool keep1 = !(pbits(kd0, kd1, t0 + HALF_T) >> 31);
  out[(size_t)r * NPX + c]          = (adj0 && keep0) ? 1 : 0;
  out[(size_t)(r + 1024) * NPX + c] = (adj1 && keep1) ? 1 : 0;
}

// ---------------- launch ----------------
extern "C" void kernel_launch(void* const* d_in, const int* in_sizes, int n_in,
                              void* d_out, int out_size, void* d_ws, size_t ws_size,
                              hipStream_t stream) {
  const float* coarse = (const float*)d_in[0];
  int* out = (int*)d_out;

  // jax.random.split under threefry_partitionable (modern default), "foldlike":
  // keys[i] = full output pair of threefry2x32(key=(0,1), counts=(hi=0, lo=i)).
  u32 a0 = 0u, a1 = 0u; tf2x32(0u, 1u, a0, a1);   // k_noise = tf(key, (0,0))
  u32 b0 = 0u, b1 = 1u; tf2x32(0u, 1u, b0, b1);   // k_drop  = tf(key, (0,1))
  const u32 kn0 = a0, kn1 = a1, kd0 = b0, kd1 = b1;

  char* ws = (char*)d_ws;
  float* pmin = (float*)ws;                       // 4096 floats
  float* pmax = (float*)(ws + 16384);             // 4096 floats

  k_pool_nostore<<<NPOOL_BLOCKS, 256, 0, stream>>>(coarse, pmin, pmax);
  k_graph_fused<<<dim3(64, 32), dim3(32, 32), 0, stream>>>(coarse, pmin, pmax, out,
                                                           kn0, kn1, kd0, kd1);
}

// Round 6
// 118.028 us; speedup vs baseline: 1.0664x; 1.0664x over previous
//
#include <hip/hip_runtime.h>

typedef unsigned int u32;

#define HALF_T 2097152u   // 2048*2048/2
#define NPX 2048
#define NPOOL_BLOCKS 4096

// ---------------- threefry2x32 (JAX-exact, 20 rounds) ----------------
__host__ __device__ inline void tf2x32(u32 k0, u32 k1, u32& x0, u32& x1) {
  const u32 ks2 = k0 ^ k1 ^ 0x1BD11BDAu;
  x0 += k0; x1 += k1;
#define TFR(r) { x0 += x1; x1 = (x1 << (r)) | (x1 >> (32 - (r))); x1 ^= x0; }
  TFR(13) TFR(15) TFR(26) TFR(6)
  x0 += k1;  x1 += ks2 + 1u;
  TFR(17) TFR(29) TFR(16) TFR(24)
  x0 += ks2; x1 += k0 + 2u;
  TFR(13) TFR(15) TFR(26) TFR(6)
  x0 += k0;  x1 += k1 + 3u;
  TFR(17) TFR(29) TFR(16) TFR(24)
  x0 += k1;  x1 += ks2 + 4u;
  TFR(13) TFR(15) TFR(26) TFR(6)
  x0 += ks2; x1 += k0 + 5u;
#undef TFR
}

// Partitionable-threefry random bits for flat index t (size < 2^32 -> hi word 0):
// bits[t] = x0 ^ x1 of threefry2x32(key, (0, t)).
__device__ inline u32 pbits(u32 k0, u32 k1, u32 t) {
  u32 x0 = 0u, x1 = t;
  tf2x32(k0, k1, x0, x1);
  return x0 ^ x1;
}

__device__ inline float bits_to_uniform(u32 bits) {
  return __uint_as_float((bits >> 9) | 0x3F800000u) - 1.0f;
}

// -------- kernel 1: maxpool + noise -> dn (one float4 store/thread) + min/max --------
// 4096 blocks x 256 threads = 1,048,576 threads; thread g -> dn row i = g>>9,
// cols 4*(g&511) .. +3. Reads coarse rows 2i, 2i+1 (two float4 each).
__global__ __launch_bounds__(256) void k_pool(const float* __restrict__ coarse,
                                              float4* __restrict__ dn4,
                                              float* __restrict__ pmin,
                                              float* __restrict__ pmax,
                                              u32 kn0, u32 kn1) {
  const u32 g = blockIdx.x * 256 + threadIdx.x;   // [0, 1048576)
  const int i  = g >> 9;                          // dn row in [0,2048)
  const int jj = g & 511;                         // float4 col group

  const float4* r0 = (const float4*)(coarse + (size_t)(2*i    ) * 4096);
  const float4* r1 = (const float4*)(coarse + (size_t)(2*i + 1) * 4096);
  const float4 a0 = r0[2*jj], a1 = r0[2*jj + 1];
  const float4 b0 = r1[2*jj], b1 = r1[2*jj + 1];

  const float p0 = fmaxf(fmaxf(a0.x, a0.y), fmaxf(b0.x, b0.y));
  const float p1 = fmaxf(fmaxf(a0.z, a0.w), fmaxf(b0.z, b0.w));
  const float p2 = fmaxf(fmaxf(a1.x, a1.y), fmaxf(b1.x, b1.y));
  const float p3 = fmaxf(fmaxf(a1.z, a1.w), fmaxf(b1.z, b1.w));

  float lmin = fminf(fminf(p0, p1), fminf(p2, p3));
  float lmax = fmaxf(fmaxf(p0, p1), fmaxf(p2, p3));

  const u32 t0 = (u32)i * 2048u + 4u * (u32)jj;
  float4 o;
  o.x = p0 + bits_to_uniform(pbits(kn0, kn1, t0));
  o.y = p1 + bits_to_uniform(pbits(kn0, kn1, t0 + 1u));
  o.z = p2 + bits_to_uniform(pbits(kn0, kn1, t0 + 2u));
  o.w = p3 + bits_to_uniform(pbits(kn0, kn1, t0 + 3u));
  dn4[g] = o;

  // wave (64) reduce, then block reduce
  for (int off = 32; off > 0; off >>= 1) {
    lmin = fminf(lmin, __shfl_down(lmin, off, 64));
    lmax = fmaxf(lmax, __shfl_down(lmax, off, 64));
  }
  __shared__ float smin[4], smax[4];
  const int lane = threadIdx.x & 63, wv = threadIdx.x >> 6;
  if (lane == 0) { smin[wv] = lmin; smax[wv] = lmax; }
  __syncthreads();
  if (threadIdx.x == 0) {
    pmin[blockIdx.x] = fminf(fminf(smin[0], smin[1]), fminf(smin[2], smin[3]));
    pmax[blockIdx.x] = fmaxf(fmaxf(smax[0], smax[1]), fmaxf(smax[2], smax[3]));
  }
}

// -------- per-block redundant final reduce (partials sit in L2/L3) --------
__device__ inline float block_thr(const float* __restrict__ pmin,
                                  const float* __restrict__ pmax,
                                  int tid) {
  __shared__ float smin[16], smax[16], sthr;
  float lmin = INFINITY, lmax = -INFINITY;
#pragma unroll
  for (int k = 0; k < NPOOL_BLOCKS; k += 1024) {
    lmin = fminf(lmin, pmin[tid + k]);
    lmax = fmaxf(lmax, pmax[tid + k]);
  }
  for (int off = 32; off > 0; off >>= 1) {
    lmin = fminf(lmin, __shfl_down(lmin, off, 64));
    lmax = fmaxf(lmax, __shfl_down(lmax, off, 64));
  }
  const int lane = tid & 63, wv = tid >> 6;
  if (lane == 0) { smin[wv] = lmin; smax[wv] = lmax; }
  __syncthreads();
  if (tid == 0) {
    float gmin = smin[0], gmax = smax[0];
#pragma unroll
    for (int w = 1; w < 16; ++w) {
      gmin = fminf(gmin, smin[w]);
      gmax = fmaxf(gmax, smax[w]);
    }
    sthr = (gmax - gmin) / 2048.0f;
  }
  __syncthreads();
  return sthr;
}

// -------- adjacency evaluation from an LDS tile --------
// s[lc][lr] = dn[i = cbase-1+lc][j = rbase-1+lr]; thread center at lc=tx+1, lr=ty+1.
__device__ inline bool adj_eval(const float s[34][35], int tx, int ty,
                                int c, int rr, float thr) {
  const float ctr = s[tx+1][ty+1];
  const bool cge1 = (c  >= 1),    cle = (c  <= NPX - 2);
  const bool rge1 = (rr >= 1),    rle = (rr <= NPX - 2);
  bool a = false;
  if (cge1 && rge1)                    a |= (fabsf(s[tx  ][ty  ] - ctr) <= thr); // d[i-1,j-1]
  if (cge1 && cle && rge1 && rle)      a |= (fabsf(s[tx+2][ty  ] - ctr) <= thr); // d[i+1,j-1]
  if (cge1 && rle)                     a |= (fabsf(s[tx  ][ty+2] - ctr) <= thr); // d[i-1,j+1]
  if (cle  && rle)                     a |= (fabsf(s[tx+2][ty+2] - ctr) <= thr); // d[i+1,j+1]
  return a;
}

// -------- kernel 2: thr reduce + adjacency + dropout; OUTPUT IS INT32 --------
__global__ __launch_bounds__(1024) void k_graph(const float* __restrict__ dn,
                                                const float* __restrict__ pmin,
                                                const float* __restrict__ pmax,
                                                int* __restrict__ out,
                                                u32 kd0, u32 kd1) {
  __shared__ float s0[34][35];
  __shared__ float s1[34][35];
  const int tid = threadIdx.y * 32 + threadIdx.x;
  const float thr = block_thr(pmin, pmax, tid);

  const int c0 = blockIdx.x * 32, r0 = blockIdx.y * 32;
  for (int idx = tid; idx < 34 * 34; idx += 1024) {
    const int lc = idx / 34, lr = idx - lc * 34;
    const int c = c0 - 1 + lc;        // dn row index (i)
    const int r = r0 - 1 + lr;        // dn col index (j), tile0
    float v0 = 0.f, v1 = 0.f;
    if ((unsigned)c < (unsigned)NPX) {
      if ((unsigned)r < (unsigned)NPX)          v0 = dn[c * NPX + r];
      const int r2 = r + 1024;
      if ((unsigned)r2 < (unsigned)NPX)         v1 = dn[c * NPX + r2];
    }
    s0[lc][lr] = v0;
    s1[lc][lr] = v1;
  }
  __syncthreads();
  const int tx = threadIdx.x, ty = threadIdx.y;
  const int c = c0 + tx, r = r0 + ty;          // out col / out row (first tile)
  const bool adj0 = adj_eval(s0, tx, ty, c, r,        thr);
  const bool adj1 = adj_eval(s1, tx, ty, c, r + 1024, thr);
  const u32 t0 = (u32)(r * NPX + c);
  // bernoulli(0.5): uniform < 0.5  <=>  top bit of bits == 0
  const bool keep0 = !(pbits(kd0, kd1, t0)          >> 31);
  const bool keep1 = !(pbits(kd0, kd1, t0 + HALF_T) >> 31);
  out[(size_t)r * NPX + c]          = (adj0 && keep0) ? 1 : 0;
  out[(size_t)(r + 1024) * NPX + c] = (adj1 && keep1) ? 1 : 0;
}

// ---------------- launch ----------------
extern "C" void kernel_launch(void* const* d_in, const int* in_sizes, int n_in,
                              void* d_out, int out_size, void* d_ws, size_t ws_size,
                              hipStream_t stream) {
  const float* coarse = (const float*)d_in[0];
  int* out = (int*)d_out;

  // jax.random.split under threefry_partitionable (modern default), "foldlike":
  // keys[i] = full output pair of threefry2x32(key=(0,1), counts=(hi=0, lo=i)).
  u32 a0 = 0u, a1 = 0u; tf2x32(0u, 1u, a0, a1);   // k_noise = tf(key, (0,0))
  u32 b0 = 0u, b1 = 1u; tf2x32(0u, 1u, b0, b1);   // k_drop  = tf(key, (0,1))
  const u32 kn0 = a0, kn1 = a1, kd0 = b0, kd1 = b1;

  char* ws = (char*)d_ws;
  float* pmin = (float*)ws;                       // 4096 floats
  float* pmax = (float*)(ws + 16384);             // 4096 floats
  float* dn   = (float*)(ws + 32768);             // 2048*2048 floats (16 MB)

  k_pool<<<NPOOL_BLOCKS, 256, 0, stream>>>(coarse, (float4*)dn, pmin, pmax, kn0, kn1);
  k_graph<<<dim3(64, 32), dim3(32, 32), 0, stream>>>(dn, pmin, pmax, out, kd0, kd1);
}